// Round 8
// baseline (501.017 us; speedup 1.0000x reference)
//
#include <hip/hip_runtime.h>
#include <stdint.h>

// BinarizeConv2dSDP: out = conv3x3(sign(x), sign(M), pad=1) * Alpha[o]
// R12: latency-chain attack (R11 showed all pipes <25% busy; stall-bound).
//   - K-steps 12 -> 6 (kh x channel-half). A stages 64B half-rows.
//   - Pipelined 1-barrier/step schedule: stage(s+1) issued BEFORE compute(s);
//     the barrier's vmcnt(0) drain lands after the whole compute phase.
//     Barriers/block: 24 -> 6.
//   - W out of LDS: direct wave-contiguous 1KB dwordx4 loads from wpk
//     (layout unchanged from R11; formula verified == R11's staged af).
//   - A granule swizzle jj=(g&3)^(pos&3) on glds16 SOURCE (LDS linear);
//     read L = pk*4 + ((2*(c0q&1)+hb)^(pk&3)) — same uniform-bank +
//     chunk<->channel semantics as R11 (absmax 0.0 verified).
// binarize_act / pack_w unchanged from R11.

typedef __attribute__((ext_vector_type(16))) float floatx16;
typedef __attribute__((ext_vector_type(8)))  int   intx8;

#define N_IMG 32
#define C_IN  256
#define O_OUT 256
#define HP 58
#define WP 58
#define GPI 3136                                    // 56*56 px per image
#define APAD_POS ((size_t)N_IMG * HP * WP)          // 107648 padded positions
#define ROWB 128                                    // 256 ch x fp4 = 128 B/pos
#define APAD_BYTES (APAD_POS * ROWB)                // 13.78 MB
#define TPI 13
#define NPOS 268                                    // staged positions per tile
#define AL_HALF (NPOS * 64)                         // 17152 B per buffer
#define WROW 8192                                   // 256 o x 32 B
#define WPK_STEP (3 * WROW)

__device__ __forceinline__ unsigned int sgn4(float x) {
    // fp4 e2m1: +1.0 = 0x2, -1.0 = 0xA, 0 = 0x0
    return x > 0.f ? 0x2u : (x < 0.f ? 0xAu : 0u);
}

__device__ __forceinline__ void glds16(const unsigned char* g, unsigned char* l) {
    __builtin_amdgcn_global_load_lds(
        (const __attribute__((address_space(1))) unsigned int*)g,
        (__attribute__((address_space(3))) unsigned int*)l, 16, 0, 0);
}

// nibble-compress: two u32 of sign-BYTES -> one u32 of sign-NIBBLES
__device__ __forceinline__ unsigned int nib16(unsigned int w) {
    return (w & 0xFu) | ((w >> 4) & 0xF0u) |
           ((w >> 8) & 0xF00u) | ((w >> 12) & 0xF000u);
}
__device__ __forceinline__ unsigned int nibc(unsigned int lo, unsigned int hi) {
    return nib16(lo) | (nib16(hi) << 16);
}

// ---------------------------------------------------------------------------
// Binarize x (NCHW fp32) -> zero-padded NHWC fp4-nibble sign buffer. (= R11)
__global__ __launch_bounds__(256) void binarize_act(
    const float* __restrict__ x, unsigned char* __restrict__ apad)
{
    int bid = blockIdx.x;
    int n = bid / HP;
    int hp = bid - n * HP;
    int tid = threadIdx.x;

    unsigned char* rowp = apad + (size_t)(n * HP + hp) * WP * ROWB;
    uint4 z = {0u, 0u, 0u, 0u};

    if (hp == 0 || hp == HP - 1) {                    // border rows: zero 58x128B
#pragma unroll
        for (int j = 0; j < 2; ++j) {
            int t = tid + 256 * j;
            if (t < WP * 8) {
                int w = t >> 3, g = t & 7;
                *(uint4*)(rowp + (size_t)w * ROWB + g * 16) = z;
            }
        }
        return;
    }
    int h = hp - 1;

    __shared__ unsigned int tile[C_IN * 15];          // [ci][word0..13], stride 15
    __shared__ unsigned int lds2[56 * 65];            // [w][cq0..63], stride 65

    const float* xb = x + ((size_t)n * C_IN) * GPI + h * 56;
#pragma unroll
    for (int j = 0; j < 14; ++j) {                    // 256 ch x 14 float4
        int t = tid + 256 * j;
        int ci = t / 14;
        int w4 = t - ci * 14;
        float4 v = *(const float4*)(xb + (size_t)ci * GPI + w4 * 4);
        tile[ci * 15 + w4] = sgn4(v.x) | (sgn4(v.y) << 8) |
                             (sgn4(v.z) << 16) | (sgn4(v.w) << 24);
    }
    __syncthreads();

#pragma unroll
    for (int j = 0; j < 14; ++j) {
        int t = tid + 256 * j;
        int wlo = t & 3;
        int cq  = (t >> 2) & 63;
        int whi = t >> 8;
        int sh = wlo * 8;
        unsigned int r = 0;
#pragma unroll
        for (int i = 0; i < 4; ++i) {
            unsigned int v = tile[(cq * 4 + i) * 15 + whi];
            r |= ((v >> sh) & 0xFFu) << (8 * i);
        }
        lds2[(whi * 4 + wlo) * 65 + cq] = r;
    }
    __syncthreads();

#pragma unroll
    for (int j = 0; j < 2; ++j) {
        int t = tid + 256 * j;                        // < 448 = 56*8
        if (t < 448) {
            int w = t >> 3, g = t & 7;
            uint4 a = *(uint4*)&lds2[w * 65 + g * 8];
            uint4 b = *(uint4*)&lds2[w * 65 + g * 8 + 4];
            uint4 v;
            v.x = nibc(a.x, a.y);
            v.y = nibc(a.z, a.w);
            v.z = nibc(b.x, b.y);
            v.w = nibc(b.z, b.w);
            *(uint4*)(rowp + (size_t)(w + 1) * ROWB + g * 16) = v;
        }
    }
    if (tid < 16) {                                   // zero pad cols 0 and 57
        int g = tid & 7;
        int col = (tid >> 3) * (WP - 1);
        *(uint4*)(rowp + (size_t)col * ROWB + g * 16) = z;
    }
}

// ---------------------------------------------------------------------------
// M (O,C,3,3) fp32 -> wpk [t=kh*4+c0q][kw][o][32B] fp4 rows. (= R11)
__global__ __launch_bounds__(64) void pack_w(
    const float* __restrict__ M, unsigned char* __restrict__ wpk)
{
    int gid = blockIdx.x * 64 + threadIdx.x;          // 16384 = 256 blk x 64
    int o = gid >> 6;
    int c4 = (gid & 63) << 2;
    int c0q = c4 >> 6;
    int half = (c4 & 63) >> 1;
    const float* mb = M + (size_t)(o * C_IN + c4) * 9;
#pragma unroll
    for (int t = 0; t < 9; ++t) {
        int kh = t / 3, kw = t - 3 * (t / 3);
        unsigned int r = sgn4(mb[t]) | (sgn4(mb[9 + t]) << 4) |
                         (sgn4(mb[18 + t]) << 8) | (sgn4(mb[27 + t]) << 12);
        size_t dst = (size_t)((kh * 4 + c0q) * 3 + kw) * WROW + o * 32 + half;
        *(unsigned short*)(wpk + dst) = (unsigned short)r;
    }
}

// ---------------------------------------------------------------------------
// Stage 268 half-rows (64B) of step s: src half-row = apad[rowbase+pos][ch2*64..]
// granule g: pos = g>>2, src chunk jj = (g&3)^(pos&3); LDS dest linear (g*16).
__device__ __forceinline__ void stage_half(const unsigned char* __restrict__ src,
    int plim, int tid, unsigned char* dst)
{
#pragma unroll
    for (int it = 0; it < 5; ++it) {
        int g = tid + (it << 8);                      // < 1072 = 268*4
        if (it < 4 || tid < 48) {
            int pos = g >> 2;
            int jj = (g & 3) ^ (pos & 3);
            int p = pos < plim ? pos : plim;
            glds16(src + (size_t)p * ROWB + (jj << 4), dst + ((size_t)g << 4));
        }
    }
}

// ---------------------------------------------------------------------------
// Implicit GEMM, MX-scaled fp4 32x32x64 MFMA; 6 steps, 1 barrier/step.
__global__ __launch_bounds__(256, 2) void bconv_gemm(
    const unsigned char* __restrict__ apad,
    const unsigned char* __restrict__ wpk,
    const float* __restrict__ alpha,
    float* __restrict__ out)
{
    __shared__ __align__(16) unsigned char Al[2][AL_HALF];     // 2 x 16.75 KB

    const int tid = threadIdx.x;
    const int wv = tid >> 6, lane = tid & 63;
    const int l31 = lane & 31, hb = lane >> 5;

    // XCD-bijective swizzle: grid 832 = 8 * 104
    const int hw = blockIdx.x;
    const int bid = (hw & 7) * 104 + (hw >> 3);

    const int img = bid / 26;
    const int rem = bid - img * 26;
    const int tl = rem >> 1, ot = rem & 1;
    const int g0 = tl << 8;
    const int h0 = g0 / 56, w0 = g0 - h0 * 56;
    const int o_base = ot << 7;
    const int Q0 = (img * HP + h0) * WP + w0;

    const int o_half  = (wv >> 1) << 6;
    const int px_half = (wv & 1) << 7;

    int pos_tab[4], pxg[4];
#pragma unroll
    for (int nt = 0; nt < 4; ++nt) {
        int px = px_half + (nt << 5) + l31;
        pxg[nt] = g0 + px;
        int pxc = (pxg[nt] < GPI) ? px : (GPI - 1 - g0);
        pos_tab[nt] = pxc + 2 * ((w0 + pxc) / 56);
    }

    floatx16 acc[2][4] = {};
    const uint4 z4 = {0u, 0u, 0u, 0u};

    // ---- prologue: stage step 0 (kh=0, low half) into Al[0]
    stage_half(apad + (size_t)Q0 * ROWB, (int)APAD_POS - 1 - Q0, tid, &Al[0][0]);

    for (int s = 0; s < 6; ++s) {                     // s = kh*2 + ch2
        const int kh = s >> 1, ch2 = s & 1;

        __syncthreads();                              // stage(s) complete

        // ---- stage step s+1 into the other buffer (lands during compute)
        if (s < 5) {
            const int s1 = s + 1;
            const int rb1 = Q0 + (s1 >> 1) * WP;
            stage_half(apad + ((size_t)rb1 * ROWB + (size_t)(s1 & 1) * 64),
                       (int)APAD_POS - 1 - rb1, tid, &Al[s1 & 1][0]);
        }

        // ---- compute from Al[s&1] + direct-W regs
        const unsigned char* AlC = &Al[s & 1][0];
#pragma unroll
        for (int cc = 0; cc < 2; ++cc) {
            const int c0q = (ch2 << 1) + cc;
            union F { uint4 q[2]; intx8 v; };
            F wf[2][3];
            const unsigned char* wb = wpk +
                (size_t)((kh * 4 + c0q) * 3) * WROW +
                (size_t)(o_base + o_half + l31) * 32 + (hb << 4);
#pragma unroll
            for (int mt = 0; mt < 2; ++mt)
#pragma unroll
                for (int kw = 0; kw < 3; ++kw) {
                    wf[mt][kw].q[0] = *(const uint4*)(wb + (size_t)kw * WROW + (size_t)mt * 1024);
                    wf[mt][kw].q[1] = z4;
                }
            const int ch = (cc << 1) | hb;            // chunk index in half-row
#pragma unroll
            for (int kw = 0; kw < 3; ++kw) {
#pragma unroll
                for (int nt = 0; nt < 4; ++nt) {
                    int pk = pos_tab[nt] + kw;
                    F bf;
                    bf.q[0] = *(const uint4*)&AlC[(size_t)(pk << 6) + ((ch ^ (pk & 3)) << 4)];
                    bf.q[1] = z4;
#pragma unroll
                    for (int mt = 0; mt < 2; ++mt)
                        acc[mt][nt] = __builtin_amdgcn_mfma_scale_f32_32x32x64_f8f6f4(
                            wf[mt][kw].v, bf.v, acc[mt][nt],
                            4, 4,                      // cbsz=blgp=fp4 e2m1
                            0, 0x7F7F7F7F,             // scale_a = 1.0
                            0, 0x7F7F7F7F);            // scale_b = 1.0
                }
            }
        }
    }

#pragma unroll
    for (int mt = 0; mt < 2; ++mt) {
#pragma unroll
        for (int r = 0; r < 16; ++r) {
            int o_loc = o_half + (mt << 5) + (r & 3) + ((r >> 2) << 3) + (hb << 2);
            int o_g = o_base + o_loc;
            float a = alpha[o_g];
            float* ob = out + ((size_t)(img * O_OUT + o_g)) * GPI;
#pragma unroll
            for (int nt = 0; nt < 4; ++nt) {
                if (pxg[nt] < GPI) ob[pxg[nt]] = acc[mt][nt][r] * a;
            }
        }
    }
}

// ---------------------------------------------------------------------------
extern "C" void kernel_launch(void* const* d_in, const int* in_sizes, int n_in,
                              void* d_out, int out_size, void* d_ws, size_t ws_size,
                              hipStream_t stream) {
    const float* x     = (const float*)d_in[0];
    const float* M     = (const float*)d_in[1];
    const float* alpha = (const float*)d_in[2];
    float* out = (float*)d_out;

    unsigned char* apad = (unsigned char*)d_ws;
    unsigned char* wpk  = apad + APAD_BYTES;

    binarize_act<<<dim3(N_IMG * HP), dim3(256), 0, stream>>>(x, apad);
    pack_w<<<dim3(256), dim3(64), 0, stream>>>(M, wpk);
    bconv_gemm<<<dim3(N_IMG * TPI * 2), dim3(256), 0, stream>>>(apad, wpk, alpha, out);
}

// Round 9
// 239.463 us; speedup vs baseline: 2.0923x; 2.0923x over previous
//
#include <hip/hip_runtime.h>
#include <stdint.h>

// BinarizeConv2dSDP: out = conv3x3(sign(x), sign(M), pad=1) * Alpha[o]
// R13: zero-barrier K-loop.
//   - A-tile for ALL 3 kh staged ONCE: 384 rows x 128 B fp4 = 48 KB LDS,
//     one __syncthreads total. K-loop has NO LDS writes, NO barriers.
//   - W read per-kw directly from L2-resident wpk (288 KB) into 16 transient
//     regs (addressing bit-verified by R12's absmax 0.0). No Wl, no wf[2][3]
//     held across regions (R12's spill: 48 regs + 128 acc > 256 cap).
//   - #pragma unroll 1 on the t-loop: prevents hoist-all-W-loads spill.
//   - Swizzle: LDS slot j of row pos holds source chunk j^(pos&7) (source-
//     side XOR, linear dest); read slot = ch^(widx&7): 8 slots x 4 banks =
//     all 32 banks per b128 = structural minimum.
//   - R11 kept: fp4 e2m1 MX MFMA (cbsz=blgp=4, unit scales), XCD swizzle,
//     epilogue, binarize_act, pack_w (all verified absmax 0.0).

typedef __attribute__((ext_vector_type(16))) float floatx16;
typedef __attribute__((ext_vector_type(8)))  int   intx8;

#define N_IMG 32
#define C_IN  256
#define O_OUT 256
#define HP 58
#define WP 58
#define GPI 3136                                    // 56*56 px per image
#define APAD_POS ((size_t)N_IMG * HP * WP)          // 107648 padded positions
#define ROWB 128                                    // 256 ch x fp4 = 128 B/pos
#define APAD_BYTES (APAD_POS * ROWB)                // 13.78 MB
#define TPI 13
#define NROWS 384                                   // 2*WP + 268 window rows
#define WROW 8192                                   // 256 o x 32 B
#define WPK_STEP (3 * WROW)

__device__ __forceinline__ unsigned int sgn4(float x) {
    // fp4 e2m1: +1.0 = 0x2, -1.0 = 0xA, 0 = 0x0
    return x > 0.f ? 0x2u : (x < 0.f ? 0xAu : 0u);
}

__device__ __forceinline__ void glds16(const unsigned char* g, unsigned char* l) {
    __builtin_amdgcn_global_load_lds(
        (const __attribute__((address_space(1))) unsigned int*)g,
        (__attribute__((address_space(3))) unsigned int*)l, 16, 0, 0);
}

// nibble-compress: two u32 of sign-BYTES -> one u32 of sign-NIBBLES
__device__ __forceinline__ unsigned int nib16(unsigned int w) {
    return (w & 0xFu) | ((w >> 4) & 0xF0u) |
           ((w >> 8) & 0xF00u) | ((w >> 12) & 0xF000u);
}
__device__ __forceinline__ unsigned int nibc(unsigned int lo, unsigned int hi) {
    return nib16(lo) | (nib16(hi) << 16);
}

// ---------------------------------------------------------------------------
// Binarize x (NCHW fp32) -> zero-padded NHWC fp4-nibble sign buffer. (= R11)
__global__ __launch_bounds__(256) void binarize_act(
    const float* __restrict__ x, unsigned char* __restrict__ apad)
{
    int bid = blockIdx.x;
    int n = bid / HP;
    int hp = bid - n * HP;
    int tid = threadIdx.x;

    unsigned char* rowp = apad + (size_t)(n * HP + hp) * WP * ROWB;
    uint4 z = {0u, 0u, 0u, 0u};

    if (hp == 0 || hp == HP - 1) {                    // border rows: zero 58x128B
#pragma unroll
        for (int j = 0; j < 2; ++j) {
            int t = tid + 256 * j;
            if (t < WP * 8) {
                int w = t >> 3, g = t & 7;
                *(uint4*)(rowp + (size_t)w * ROWB + g * 16) = z;
            }
        }
        return;
    }
    int h = hp - 1;

    __shared__ unsigned int tile[C_IN * 15];          // [ci][word0..13], stride 15
    __shared__ unsigned int lds2[56 * 65];            // [w][cq0..63], stride 65

    const float* xb = x + ((size_t)n * C_IN) * GPI + h * 56;
#pragma unroll
    for (int j = 0; j < 14; ++j) {                    // 256 ch x 14 float4
        int t = tid + 256 * j;
        int ci = t / 14;
        int w4 = t - ci * 14;
        float4 v = *(const float4*)(xb + (size_t)ci * GPI + w4 * 4);
        tile[ci * 15 + w4] = sgn4(v.x) | (sgn4(v.y) << 8) |
                             (sgn4(v.z) << 16) | (sgn4(v.w) << 24);
    }
    __syncthreads();

#pragma unroll
    for (int j = 0; j < 14; ++j) {
        int t = tid + 256 * j;
        int wlo = t & 3;
        int cq  = (t >> 2) & 63;
        int whi = t >> 8;
        int sh = wlo * 8;
        unsigned int r = 0;
#pragma unroll
        for (int i = 0; i < 4; ++i) {
            unsigned int v = tile[(cq * 4 + i) * 15 + whi];
            r |= ((v >> sh) & 0xFFu) << (8 * i);
        }
        lds2[(whi * 4 + wlo) * 65 + cq] = r;
    }
    __syncthreads();

#pragma unroll
    for (int j = 0; j < 2; ++j) {
        int t = tid + 256 * j;                        // < 448 = 56*8
        if (t < 448) {
            int w = t >> 3, g = t & 7;
            uint4 a = *(uint4*)&lds2[w * 65 + g * 8];
            uint4 b = *(uint4*)&lds2[w * 65 + g * 8 + 4];
            uint4 v;
            v.x = nibc(a.x, a.y);
            v.y = nibc(a.z, a.w);
            v.z = nibc(b.x, b.y);
            v.w = nibc(b.z, b.w);
            *(uint4*)(rowp + (size_t)(w + 1) * ROWB + g * 16) = v;
        }
    }
    if (tid < 16) {                                   // zero pad cols 0 and 57
        int g = tid & 7;
        int col = (tid >> 3) * (WP - 1);
        *(uint4*)(rowp + (size_t)col * ROWB + g * 16) = z;
    }
}

// ---------------------------------------------------------------------------
// M (O,C,3,3) fp32 -> wpk [t=kh*4+c0q][kw][o][32B] fp4 rows. (= R11)
__global__ __launch_bounds__(64) void pack_w(
    const float* __restrict__ M, unsigned char* __restrict__ wpk)
{
    int gid = blockIdx.x * 64 + threadIdx.x;          // 16384 = 256 blk x 64
    int o = gid >> 6;
    int c4 = (gid & 63) << 2;
    int c0q = c4 >> 6;
    int half = (c4 & 63) >> 1;
    const float* mb = M + (size_t)(o * C_IN + c4) * 9;
#pragma unroll
    for (int t = 0; t < 9; ++t) {
        int kh = t / 3, kw = t - 3 * (t / 3);
        unsigned int r = sgn4(mb[t]) | (sgn4(mb[9 + t]) << 4) |
                         (sgn4(mb[18 + t]) << 8) | (sgn4(mb[27 + t]) << 12);
        size_t dst = (size_t)((kh * 4 + c0q) * 3 + kw) * WROW + o * 32 + half;
        *(unsigned short*)(wpk + dst) = (unsigned short)r;
    }
}

// ---------------------------------------------------------------------------
// Implicit GEMM, MX-scaled fp4 32x32x64 MFMA; A staged once, zero-barrier loop.
__global__ __launch_bounds__(256, 2) void bconv_gemm(
    const unsigned char* __restrict__ apad,
    const unsigned char* __restrict__ wpk,
    const float* __restrict__ alpha,
    float* __restrict__ out)
{
    __shared__ __align__(16) unsigned char Al[NROWS * ROWB];   // 48 KB

    const int tid = threadIdx.x;
    const int wv = tid >> 6, lane = tid & 63;
    const int l31 = lane & 31, hb = lane >> 5;

    // XCD-bijective swizzle: grid 832 = 8 * 104
    const int hw = blockIdx.x;
    const int bid = (hw & 7) * 104 + (hw >> 3);

    const int img = bid / 26;
    const int rem = bid - img * 26;
    const int tl = rem >> 1, ot = rem & 1;
    const int g0 = tl << 8;
    const int h0 = g0 / 56, w0 = g0 - h0 * 56;
    const int o_base = ot << 7;
    const int Q0 = (img * HP + h0) * WP + w0;

    const int o_half  = (wv >> 1) << 6;
    const int px_half = (wv & 1) << 7;

    int pos_tab[4], pxg[4];
#pragma unroll
    for (int nt = 0; nt < 4; ++nt) {
        int px = px_half + (nt << 5) + l31;
        pxg[nt] = g0 + px;
        int pxc = (pxg[nt] < GPI) ? px : (GPI - 1 - g0);
        pos_tab[nt] = pxc + 2 * ((w0 + pxc) / 56);
    }

    floatx16 acc[2][4] = {};
    const uint4 z4 = {0u, 0u, 0u, 0u};

    // ---- prologue: stage the WHOLE 3-kh A window (384 rows x 128 B), once.
    // granule g: pos = g>>3, LDS slot j = g&7 holds source chunk j^(pos&7).
    {
        const int plim = (int)APAD_POS - 1 - Q0;
        const unsigned char* asrc = apad + (size_t)Q0 * ROWB;
#pragma unroll
        for (int it = 0; it < 12; ++it) {             // 3072 granules / 256 thr
            int g = (it << 8) + tid;
            int pos = g >> 3;
            int sc = (g & 7) ^ (pos & 7);
            int p = pos < plim ? pos : plim;
            glds16(asrc + (size_t)p * ROWB + (sc << 4), &Al[(size_t)g << 4]);
        }
    }
    __syncthreads();                                  // the ONLY barrier

#pragma unroll 1
    for (int t = 0; t < 12; ++t) {                    // t = kh*4 + c0q
        const int kh = t >> 2;
        const int khW = kh * WP;
        const int ch = ((t & 3) << 1) | hb;           // chunk in 128B row
        const unsigned char* wb = wpk + (size_t)t * WPK_STEP +
            (size_t)(o_base + o_half + l31) * 32 + (hb << 4);
#pragma unroll
        for (int kw = 0; kw < 3; ++kw) {
            union F { uint4 q[2]; intx8 v; };
            F wf0, wf1;
            wf0.q[0] = *(const uint4*)(wb + (size_t)kw * WROW);
            wf0.q[1] = z4;
            wf1.q[0] = *(const uint4*)(wb + (size_t)kw * WROW + 1024);
            wf1.q[1] = z4;
#pragma unroll
            for (int nt = 0; nt < 4; ++nt) {
                int widx = khW + pos_tab[nt] + kw;
                F bf;
                bf.q[0] = *(const uint4*)&Al[(size_t)(widx << 7) +
                                             ((ch ^ (widx & 7)) << 4)];
                bf.q[1] = z4;
                acc[0][nt] = __builtin_amdgcn_mfma_scale_f32_32x32x64_f8f6f4(
                    wf0.v, bf.v, acc[0][nt],
                    4, 4, 0, 0x7F7F7F7F, 0, 0x7F7F7F7F);
                acc[1][nt] = __builtin_amdgcn_mfma_scale_f32_32x32x64_f8f6f4(
                    wf1.v, bf.v, acc[1][nt],
                    4, 4, 0, 0x7F7F7F7F, 0, 0x7F7F7F7F);
            }
        }
    }

#pragma unroll
    for (int mt = 0; mt < 2; ++mt) {
#pragma unroll
        for (int r = 0; r < 16; ++r) {
            int o_loc = o_half + (mt << 5) + (r & 3) + ((r >> 2) << 3) + (hb << 2);
            int o_g = o_base + o_loc;
            float a = alpha[o_g];
            float* ob = out + ((size_t)(img * O_OUT + o_g)) * GPI;
#pragma unroll
            for (int nt = 0; nt < 4; ++nt) {
                if (pxg[nt] < GPI) ob[pxg[nt]] = acc[mt][nt][r] * a;
            }
        }
    }
}

// ---------------------------------------------------------------------------
extern "C" void kernel_launch(void* const* d_in, const int* in_sizes, int n_in,
                              void* d_out, int out_size, void* d_ws, size_t ws_size,
                              hipStream_t stream) {
    const float* x     = (const float*)d_in[0];
    const float* M     = (const float*)d_in[1];
    const float* alpha = (const float*)d_in[2];
    float* out = (float*)d_out;

    unsigned char* apad = (unsigned char*)d_ws;
    unsigned char* wpk  = apad + APAD_BYTES;

    binarize_act<<<dim3(N_IMG * HP), dim3(256), 0, stream>>>(x, apad);
    pack_w<<<dim3(256), dim3(64), 0, stream>>>(M, wpk);
    bconv_gemm<<<dim3(N_IMG * TPI * 2), dim3(256), 0, stream>>>(apad, wpk, alpha, out);
}